// Round 1
// baseline (2295.780 us; speedup 1.0000x reference)
//
#include <hip/hip_runtime.h>

#define NB 512      // N
#define KNB 30      // neighbors
#define HID 128
#define NL 3
#define NOUT 400
#define NHEADS 4
#define DHEAD 32
#define NFF 512
#define KP 32       // padded rows
#define HP 132      // padded LDS row stride (%32==4, %4==0)

__device__ __forceinline__ void fma4(float* acc, float a, float4 w) {
  acc[0] = fmaf(a, w.x, acc[0]);
  acc[1] = fmaf(a, w.y, acc[1]);
  acc[2] = fmaf(a, w.z, acc[2]);
  acc[3] = fmaf(a, w.w, acc[3]);
}

// h_V = V @ Wv + bv   (1024 x 128) — tiny
__global__ void k_hv(const float* __restrict__ V, const float* __restrict__ Wv,
                     const float* __restrict__ bv, float* __restrict__ hV) {
  int idx = blockIdx.x * 256 + threadIdx.x;   // 512 blocks -> 131072
  int row = idx >> 7, c = idx & 127;
  const float* vr = V + row * HID;
  float acc = bv[c];
  for (int i = 0; i < HID; ++i) acc = fmaf(vr[i], Wv[i * HID + c], acc);
  hV[idx] = acc;
}

// LN in place on hE rows<30; mmul applies trailing x_mask multiply
__device__ __forceinline__ void layer_norm(float (*hE)[HP], const float* __restrict__ g,
                                           const float* __restrict__ bb, float mmul, int tid) {
  int r = tid >> 3, g8 = tid & 7;
  if (r < KNB) {
    float x[16]; float s1 = 0.f, s2 = 0.f;
    int cb = g8 * 16;
#pragma unroll
    for (int m = 0; m < 16; ++m) { x[m] = hE[r][cb + m]; s1 += x[m]; s2 += x[m] * x[m]; }
#pragma unroll
    for (int o = 1; o < 8; o <<= 1) { s1 += __shfl_xor(s1, o); s2 += __shfl_xor(s2, o); }
    float mu = s1 * (1.f / 128.f);
    float var = fmaf(-s1, mu, s2) * (1.f / 127.f);      // (s2 - s1^2/128)/127
    float inv = 1.f / (sqrtf(var + 1e-6f) + 1e-6f);
#pragma unroll
    for (int m = 0; m < 16; ++m) {
      int c = cb + m;
      hE[r][c] = (g[c] * (x[m] - mu) * inv + bb[c]) * mmul;
    }
  }
}

__launch_bounds__(256, 1)
__global__ void k_main(
    const float* __restrict__ E, const int* __restrict__ Eix, const float* __restrict__ xm,
    const float* __restrict__ We, const float* __restrict__ be,
    const float* __restrict__ WQ, const float* __restrict__ WK,
    const float* __restrict__ WVp, const float* __restrict__ WO,
    const float* __restrict__ l1g, const float* __restrict__ l1b,
    const float* __restrict__ l2g, const float* __restrict__ l2b,
    const float* __restrict__ f1w, const float* __restrict__ f1b,
    const float* __restrict__ f2w, const float* __restrict__ f2b,
    const float* __restrict__ Wout, const float* __restrict__ bout,
    const float* __restrict__ hV, float* __restrict__ gOUT) {
  __shared__ float hE[KP][HP];
  __shared__ float hJ[KP][HID];
  __shared__ float hI[HID];
  __shared__ float bufA[KP][HP];        // E-tile, then Q, then V, then FF chunk
  __shared__ float KtU[HID * 33];       // K^T [128][33]; later upd [32*128]
  __shared__ float att[NHEADS][KP][33];
  __shared__ float kadd[HID];
  __shared__ float vadd[HID];
  __shared__ float ma[KNB];
  __shared__ int eidx[KNB];

  const int tid = threadIdx.x;
  const int bid = blockIdx.x;
  const int b = bid >> 9;
  const int n = bid & (NB - 1);
  const int rg = tid >> 5, cg = tid & 31;
  const int r0 = rg * 4, c0 = cg * 4;

  // ---------------- init ----------------
  for (int x = tid; x < KP * HP; x += 256) { (&hE[0][0])[x] = 0.f; (&bufA[0][0])[x] = 0.f; }
  for (int x = tid; x < NHEADS * KP * 33; x += 256) (&att[0][0][0])[x] = 0.f;
  for (int x = tid; x < KP * HID; x += 256) (&hJ[0][0])[x] = 0.f;
  if (tid < KNB) eidx[tid] = Eix[(b * NB + n) * KNB + tid];
  __syncthreads();
  const float mrow = xm[b * NB + n];
  if (tid < KNB) ma[tid] = xm[b * NB + eidx[tid]] * mrow;
  if (tid < HID) hI[tid] = hV[(b * NB + eidx[0]) * HID + tid];
  for (int x = tid; x < KNB * HID; x += 256) {
    int r = x >> 7, c = x & 127;
    bufA[r][c] = E[(size_t)((b * NB + n) * KNB) * HID + x];
    hJ[r][c] = hV[(b * NB + eidx[r]) * HID + c];
  }
  __syncthreads();

  // hE = E_tile @ We + be
  {
    float acc[4][4] = {{0.f}};
    for (int i = 0; i < HID; ++i) {
      float4 w4 = *(const float4*)(We + i * HID + c0);
#pragma unroll
      for (int jr = 0; jr < 4; ++jr) fma4(acc[jr], bufA[r0 + jr][i], w4);
    }
    __syncthreads();
#pragma unroll
    for (int jr = 0; jr < 4; ++jr) {
      int r = r0 + jr;
      if (r < KNB) {
#pragma unroll
        for (int j = 0; j < 4; ++j) hE[r][c0 + j] = acc[jr][j] + be[c0 + j];
      }
    }
  }
  __syncthreads();

  // ---------------- layers ----------------
  for (int l = 0; l < NL; ++l) {
    const float* wq = WQ + l * HID * HID;
    const float* wk = WK + l * 3 * HID * HID;
    const float* wv = WVp + l * 3 * HID * HID;
    const float* wo = WO + l * HID * HID;
    const float* f1 = f1w + l * HID * NFF;
    const float* b1 = f1b + l * NFF;
    const float* f2 = f2w + l * NFF * HID;
    const float* b2 = f2b + l * HID;

    // A: rank-1 h_i contributions: kadd/vadd[c] = sum_i hI[i]*w[i][c]
    {
      const float* w = (tid < HID) ? wk : wv;   // wave-uniform
      int c = tid & 127;
      float acc = 0.f;
      for (int i = 0; i < HID; ++i) acc = fmaf(hI[i], w[i * HID + c], acc);
      if (tid < HID) kadd[c] = acc; else vadd[c] = acc;
    }
    __syncthreads();

    // B: Q (hE@wq) -> bufA; K (hEV@wk) -> KtU transposed; V kept in regs
    float vv[4][4];
    {
      float qq[4][4] = {{0.f}}; float kk[4][4] = {{0.f}};
#pragma unroll
      for (int jr = 0; jr < 4; ++jr)
#pragma unroll
        for (int j = 0; j < 4; ++j) vv[jr][j] = 0.f;
      for (int i = 0; i < HID; ++i) {
        float4 wq4 = *(const float4*)(wq + i * HID + c0);
        float4 wkj = *(const float4*)(wk + (HID + i) * HID + c0);
        float4 wke = *(const float4*)(wk + (2 * HID + i) * HID + c0);
        float4 wvj = *(const float4*)(wv + (HID + i) * HID + c0);
        float4 wve = *(const float4*)(wv + (2 * HID + i) * HID + c0);
#pragma unroll
        for (int jr = 0; jr < 4; ++jr) {
          float ae = hE[r0 + jr][i];
          float aj = hJ[r0 + jr][i];
          fma4(qq[jr], ae, wq4);
          fma4(kk[jr], aj, wkj);
          fma4(kk[jr], ae, wke);
          fma4(vv[jr], aj, wvj);
          fma4(vv[jr], ae, wve);
        }
      }
#pragma unroll
      for (int jr = 0; jr < 4; ++jr)
        *(float4*)&bufA[r0 + jr][c0] = make_float4(qq[jr][0], qq[jr][1], qq[jr][2], qq[jr][3]);
#pragma unroll
      for (int jr = 0; jr < 4; ++jr)
#pragma unroll
        for (int j = 0; j < 4; ++j)
          KtU[(c0 + j) * 33 + (r0 + jr)] = kk[jr][j] + kadd[c0 + j];
#pragma unroll
      for (int jr = 0; jr < 4; ++jr)
#pragma unroll
        for (int j = 0; j < 4; ++j) vv[jr][j] += vadd[c0 + j];
    }
    __syncthreads();

    // C: logits (masked) -> att
    {
      const float scale = 0.17677669529663687f;  // 1/sqrt(32)
      for (int idx = tid; idx < NHEADS * KNB * KNB; idx += 256) {
        int h = idx / (KNB * KNB);
        int rem = idx % (KNB * KNB);
        int q = rem / KNB, k = rem % KNB;
        const float* qrow = &bufA[q][h * DHEAD];
        const float* krow = &KtU[(h * DHEAD) * 33 + k];
        float acc = 0.f;
#pragma unroll
        for (int d = 0; d < DHEAD; ++d) acc = fmaf(qrow[d], krow[d * 33], acc);
        acc *= scale;
        float m = ma[q] * ma[k];
        att[h][q][k] = (m > 0.f) ? acc : -3.4028234663852886e38f;
      }
    }
    __syncthreads();
    // softmax per (h,q) row; all threads also dump V(regs) -> bufA (Q is dead)
    if (tid < NHEADS * KNB) {
      int h = tid / KNB, q = tid % KNB;
      float mx = -3.4028234663852886e38f;
      for (int k = 0; k < KNB; ++k) mx = fmaxf(mx, att[h][q][k]);
      float s = 0.f;
      for (int k = 0; k < KNB; ++k) { float e = expf(att[h][q][k] - mx); att[h][q][k] = e; s += e; }
      float inv = 1.f / s;
      float mq = ma[q];
      for (int k = 0; k < KNB; ++k) att[h][q][k] = att[h][q][k] * inv * (mq * ma[k]);
    }
#pragma unroll
    for (int jr = 0; jr < 4; ++jr)
      *(float4*)&bufA[r0 + jr][c0] = make_float4(vv[jr][0], vv[jr][1], vv[jr][2], vv[jr][3]);
    __syncthreads();

    // E: upd = att @ V -> updf (aliases KtU, row-major [32][128])
    float* updf = KtU;
    {
      int h = cg >> 3;   // = c0/32, constant per thread
      float u[4][4] = {{0.f}};
      for (int k = 0; k < KNB; ++k) {
        float4 v4 = *(const float4*)&bufA[k][c0];
#pragma unroll
        for (int jr = 0; jr < 4; ++jr) fma4(u[jr], att[h][r0 + jr][k], v4);
      }
#pragma unroll
      for (int jr = 0; jr < 4; ++jr)
#pragma unroll
        for (int j = 0; j < 4; ++j) updf[(r0 + jr) * HID + c0 + j] = u[jr][j];
    }
    __syncthreads();

    // F: dh = upd @ wo ; hE += dh
    {
      float acc[4][4] = {{0.f}};
      for (int i = 0; i < HID; ++i) {
        float4 w4 = *(const float4*)(wo + i * HID + c0);
#pragma unroll
        for (int jr = 0; jr < 4; ++jr) fma4(acc[jr], updf[(r0 + jr) * HID + i], w4);
      }
#pragma unroll
      for (int jr = 0; jr < 4; ++jr) {
        int r = r0 + jr;
        if (r < KNB) {
#pragma unroll
          for (int j = 0; j < 4; ++j) hE[r][c0 + j] += acc[jr][j];
        }
      }
    }
    __syncthreads();

    // G: LN1
    layer_norm(hE, l1g + l * HID, l1b + l * HID, 1.f, tid);
    __syncthreads();

    // H: FF in 4 chunks of 128 (t chunk staged in bufA)
    {
      float facc[4][4] = {{0.f}};
      for (int ch = 0; ch < 4; ++ch) {
        float acc[4][4] = {{0.f}};
        for (int i = 0; i < HID; ++i) {
          float4 w4 = *(const float4*)(f1 + i * NFF + ch * HID + c0);
#pragma unroll
          for (int jr = 0; jr < 4; ++jr) fma4(acc[jr], hE[r0 + jr][i], w4);
        }
#pragma unroll
        for (int jr = 0; jr < 4; ++jr)
#pragma unroll
          for (int j = 0; j < 4; ++j)
            bufA[r0 + jr][c0 + j] = fmaxf(acc[jr][j] + b1[ch * HID + c0 + j], 0.f);
        __syncthreads();
        for (int i = 0; i < HID; ++i) {
          float4 w4 = *(const float4*)(f2 + (ch * HID + i) * HID + c0);
#pragma unroll
          for (int jr = 0; jr < 4; ++jr) fma4(facc[jr], bufA[r0 + jr][i], w4);
        }
        __syncthreads();
      }
#pragma unroll
      for (int jr = 0; jr < 4; ++jr) {
        int r = r0 + jr;
        if (r < KNB) {
#pragma unroll
          for (int j = 0; j < 4; ++j) hE[r][c0 + j] += facc[jr][j] + b2[c0 + j];
        }
      }
    }
    __syncthreads();

    // I: LN2 + x_mask multiply
    layer_norm(hE, l2g + l * HID, l2b + l * HID, mrow, tid);
    __syncthreads();
  }

  // ---------------- h_out = hE @ Wout + bout ----------------
  {
    float* gO = gOUT + (size_t)((b * NB + n) * KNB) * NOUT;
    for (int p = 0; p < 4; ++p) {
      int cc0 = p * HID + c0;
      if (cc0 < NOUT) {
        float acc[4][4] = {{0.f}};
        for (int i = 0; i < HID; ++i) {
          float4 w4 = *(const float4*)(Wout + i * NOUT + cc0);
#pragma unroll
          for (int jr = 0; jr < 4; ++jr) fma4(acc[jr], hE[r0 + jr][i], w4);
        }
        float4 b4 = *(const float4*)(bout + cc0);
#pragma unroll
        for (int jr = 0; jr < 4; ++jr) {
          int r = r0 + jr;
          if (r < KNB) {
            *(float4*)(gO + r * NOUT + cc0) =
                make_float4(acc[jr][0] + b4.x, acc[jr][1] + b4.y, acc[jr][2] + b4.z, acc[jr][3] + b4.w);
          }
        }
      }
    }
  }
}

// ---- merge_duplicate_edges ----
__global__ void k_clearT(int* __restrict__ T) {
  int i = blockIdx.x * 256 + threadIdx.x;
  if (i < 2 * NB * NB) T[i] = 0;
}
__global__ void k_buildT(const int* __restrict__ Eix, int* __restrict__ T) {
  int idx = blockIdx.x * 256 + threadIdx.x;   // 2*512*30
  if (idx < 2 * NB * KNB) {
    int b = idx / (NB * KNB);
    int rem = idx % (NB * KNB);
    int i = rem / KNB, k = rem % KNB;
    int j = Eix[idx];
    atomicMax(&T[(b * NB + i) * NB + j], k + 1);   // last-write-wins
  }
}
__global__ void k_merge(const float* __restrict__ HO, const int* __restrict__ Eix,
                        const int* __restrict__ T, float* __restrict__ out) {
  int gid = blockIdx.x * 256 + threadIdx.x;   // 2*512*30*100
  if (gid >= 2 * NB * KNB * (NOUT / 4)) return;
  int c4 = gid % (NOUT / 4);
  int bnk = gid / (NOUT / 4);
  int b = bnk / (NB * KNB);
  int n = (bnk / KNB) % NB;
  int j = Eix[bnk];
  int kp = T[(b * NB + j) * NB + n];
  float4 a = ((const float4*)HO)[(size_t)bnk * (NOUT / 4) + c4];
  float4 rv = make_float4(0.f, 0.f, 0.f, 0.f);
  if (kp > 0) rv = ((const float4*)HO)[(size_t)((b * NB + j) * KNB + (kp - 1)) * (NOUT / 4) + c4];
  ((float4*)out)[gid] = make_float4(0.5f * (a.x + rv.x), 0.5f * (a.y + rv.y),
                                    0.5f * (a.z + rv.z), 0.5f * (a.w + rv.w));
}

extern "C" void kernel_launch(void* const* d_in, const int* in_sizes, int n_in,
                              void* d_out, int out_size, void* d_ws, size_t ws_size,
                              hipStream_t stream) {
  const float* V   = (const float*)d_in[0];
  const float* E   = (const float*)d_in[1];
  const float* xmk = (const float*)d_in[2];
  const int*   Eix = (const int*)d_in[3];
  const float* Wv  = (const float*)d_in[4];
  const float* bv  = (const float*)d_in[5];
  const float* We  = (const float*)d_in[6];
  const float* be  = (const float*)d_in[7];
  const float* WQ  = (const float*)d_in[8];
  const float* WK  = (const float*)d_in[9];
  const float* WVp = (const float*)d_in[10];
  const float* WO  = (const float*)d_in[11];
  const float* l1g = (const float*)d_in[12];
  const float* l1b = (const float*)d_in[13];
  const float* l2g = (const float*)d_in[14];
  const float* l2b = (const float*)d_in[15];
  const float* f1w = (const float*)d_in[16];
  const float* f1b = (const float*)d_in[17];
  const float* f2w = (const float*)d_in[18];
  const float* f2b = (const float*)d_in[19];
  const float* Wou = (const float*)d_in[20];
  const float* bou = (const float*)d_in[21];

  // ws layout: HO (12,288,000 f) | T (524,288 i) | hV (131,072 f)  ~49.4 MiB
  float* HO = (float*)d_ws;
  int*   T  = (int*)((char*)d_ws + 12288000ull * 4);
  float* hV = (float*)((char*)d_ws + (12288000ull + 524288ull) * 4);

  k_hv<<<512, 256, 0, stream>>>(V, Wv, bv, hV);
  k_main<<<1024, 256, 0, stream>>>(E, Eix, xmk, We, be, WQ, WK, WVp, WO,
                                   l1g, l1b, l2g, l2b, f1w, f1b, f2w, f2b,
                                   Wou, bou, hV, HO);
  k_clearT<<<2048, 256, 0, stream>>>(T);
  k_buildT<<<120, 256, 0, stream>>>(Eix, T);
  k_merge<<<12000, 256, 0, stream>>>(HO, Eix, T, (float*)d_out);
}

// Round 2
// 1094.435 us; speedup vs baseline: 2.0977x; 2.0977x over previous
//
#include <hip/hip_runtime.h>

#define NB 512      // N
#define KNB 30      // neighbors
#define HID 128
#define NL 3
#define NOUT 400
#define NHEADS 4
#define DHEAD 32
#define NFF 512
#define KP 32       // padded rows
#define HP 132      // padded LDS row stride

__device__ __forceinline__ void fma4(float* acc, float a, float4 w) {
  acc[0] = fmaf(a, w.x, acc[0]);
  acc[1] = fmaf(a, w.y, acc[1]);
  acc[2] = fmaf(a, w.z, acc[2]);
  acc[3] = fmaf(a, w.w, acc[3]);
}

// h_V = V @ Wv + bv   (1024 x 128)
__global__ void k_hv(const float* __restrict__ V, const float* __restrict__ Wv,
                     const float* __restrict__ bv, float* __restrict__ hV) {
  int idx = blockIdx.x * 256 + threadIdx.x;   // 512 blocks -> 131072
  int row = idx >> 7, c = idx & 127;
  const float* vr = V + row * HID;
  float acc = bv[c];
  for (int i = 0; i < HID; ++i) acc = fmaf(vr[i], Wv[i * HID + c], acc);
  hV[idx] = acc;
}

// Precompute node-side K/V projections for all layers:
// t = l*4 + {0:Ki, 1:Kj, 2:Vi, 3:Vj}; tbl[t][row][c] = hV[row] . W[:,c]
__global__ void k_tables(const float* __restrict__ hV, const float* __restrict__ WK,
                         const float* __restrict__ WVp, float* __restrict__ tbl) {
  int idx = blockIdx.x * 256 + threadIdx.x;   // 6144 blocks -> 1,572,864
  int c = idx & 127;
  int row = (idx >> 7) & 1023;
  int t = idx >> 17;                 // 0..11
  int l = t >> 2, part = t & 3;
  const float* W;
  if (part == 0)      W = WK  + l * 3 * HID * HID;              // h_i rows of WK
  else if (part == 1) W = WK  + l * 3 * HID * HID + HID * HID;  // h_j rows of WK
  else if (part == 2) W = WVp + l * 3 * HID * HID;              // h_i rows of WV
  else                W = WVp + l * 3 * HID * HID + HID * HID;  // h_j rows of WV
  const float* hr = hV + row * HID;
  float acc = 0.f;
  for (int i = 0; i < HID; ++i) acc = fmaf(hr[i], W[i * HID + c], acc);
  tbl[idx] = acc;
}

// LN in place on hE rows<30; mmul applies trailing x_mask multiply
__device__ __forceinline__ void layer_norm(float (*hE)[HP], const float* __restrict__ g,
                                           const float* __restrict__ bb, float mmul, int tid) {
  int r = tid >> 3, g8 = tid & 7;
  if (r < KNB) {
    float x[16]; float s1 = 0.f, s2 = 0.f;
    int cb = g8 * 16;
#pragma unroll
    for (int m = 0; m < 16; ++m) { x[m] = hE[r][cb + m]; s1 += x[m]; s2 += x[m] * x[m]; }
#pragma unroll
    for (int o = 1; o < 8; o <<= 1) { s1 += __shfl_xor(s1, o); s2 += __shfl_xor(s2, o); }
    float mu = s1 * (1.f / 128.f);
    float var = fmaf(-s1, mu, s2) * (1.f / 127.f);
    float inv = 1.f / (sqrtf(var + 1e-6f) + 1e-6f);
#pragma unroll
    for (int m = 0; m < 16; ++m) {
      int c = cb + m;
      hE[r][c] = (g[c] * (x[m] - mu) * inv + bb[c]) * mmul;
    }
  }
}

__launch_bounds__(256, 2)
__global__ void k_main(
    const float* __restrict__ E, const int* __restrict__ Eix, const float* __restrict__ xm,
    const float* __restrict__ We, const float* __restrict__ be,
    const float* __restrict__ WQ, const float* __restrict__ WK,
    const float* __restrict__ WVp, const float* __restrict__ WO,
    const float* __restrict__ l1g, const float* __restrict__ l1b,
    const float* __restrict__ l2g, const float* __restrict__ l2b,
    const float* __restrict__ f1w, const float* __restrict__ f1b,
    const float* __restrict__ f2w, const float* __restrict__ f2b,
    const float* __restrict__ Wout, const float* __restrict__ bout,
    const float* __restrict__ tbl, float* __restrict__ gOUT) {
  __shared__ float hE[KP][HP];
  __shared__ float bufA[KP][HP];        // E-tile, then Q, then V, then FF chunk
  __shared__ float KtU[HID * 33];       // K^T [128][33]; later upd [32*128]
  __shared__ float att[NHEADS][KP][33];
  __shared__ float ma[KP];
  __shared__ int eidx[KP];

  const int tid = threadIdx.x;
  const int bid = blockIdx.x;
  const int b = bid >> 9;
  const int n = bid & (NB - 1);
  const int rg = tid >> 5, cg = tid & 31;
  const int r0 = rg * 4, c0 = cg * 4;

  // ---------------- init ----------------
  for (int x = tid; x < KP * HP; x += 256) { (&hE[0][0])[x] = 0.f; (&bufA[0][0])[x] = 0.f; }
  for (int x = tid; x < NHEADS * KP * 33; x += 256) (&att[0][0][0])[x] = 0.f;
  if (tid < KP) eidx[tid] = (tid < KNB) ? Eix[(b * NB + n) * KNB + tid] : 0;
  __syncthreads();
  const float mrow = xm[b * NB + n];
  if (tid < KP) ma[tid] = (tid < KNB) ? xm[b * NB + eidx[tid]] * mrow : 0.f;
  for (int x = tid; x < KNB * HID; x += 256) {
    int r = x >> 7, c = x & 127;
    bufA[r][c] = E[(size_t)((b * NB + n) * KNB) * HID + x];
  }
  __syncthreads();

  // hE = E_tile @ We + be
  {
    float acc[4][4] = {{0.f}};
    for (int i = 0; i < HID; ++i) {
      float4 w4 = *(const float4*)(We + i * HID + c0);
#pragma unroll
      for (int jr = 0; jr < 4; ++jr) fma4(acc[jr], bufA[r0 + jr][i], w4);
    }
    __syncthreads();
#pragma unroll
    for (int jr = 0; jr < 4; ++jr) {
      int r = r0 + jr;
      if (r < KNB) {
#pragma unroll
        for (int j = 0; j < 4; ++j) hE[r][c0 + j] = acc[jr][j] + be[c0 + j];
      }
    }
  }
  __syncthreads();

  // ---------------- layers ----------------
  for (int l = 0; l < NL; ++l) {
    const float* wq  = WQ  + l * HID * HID;
    const float* wkE = WK  + l * 3 * HID * HID + 2 * HID * HID;
    const float* wvE = WVp + l * 3 * HID * HID + 2 * HID * HID;
    const float* wo  = WO  + l * HID * HID;
    const float* f1 = f1w + l * HID * NFF;
    const float* b1 = f1b + l * NFF;
    const float* f2 = f2w + l * NFF * HID;
    const float* b2 = f2b + l * HID;
    const float* Ki = tbl + (size_t)(l * 4 + 0) * (2 * NB * HID) + (size_t)b * NB * HID;
    const float* Kj = tbl + (size_t)(l * 4 + 1) * (2 * NB * HID) + (size_t)b * NB * HID;
    const float* Vi = tbl + (size_t)(l * 4 + 2) * (2 * NB * HID) + (size_t)b * NB * HID;
    const float* Vj = tbl + (size_t)(l * 4 + 3) * (2 * NB * HID) + (size_t)b * NB * HID;

    // B: Q (hE@wq) -> bufA; K = hE@wkE + gather -> KtU^T; V = hE@wvE + gather (regs)
    float vv[4][4];
    {
      float qq[4][4] = {{0.f}}; float kk[4][4] = {{0.f}};
#pragma unroll
      for (int jr = 0; jr < 4; ++jr)
#pragma unroll
        for (int j = 0; j < 4; ++j) vv[jr][j] = 0.f;
      const int e0 = eidx[0];
      float4 ka = *(const float4*)(Ki + e0 * HID + c0);
      float4 va = *(const float4*)(Vi + e0 * HID + c0);
      float4 kj4[4], vj4[4];
#pragma unroll
      for (int jr = 0; jr < 4; ++jr) {
        int e = eidx[r0 + jr];
        kj4[jr] = *(const float4*)(Kj + e * HID + c0);
        vj4[jr] = *(const float4*)(Vj + e * HID + c0);
      }
      for (int i = 0; i < HID; ++i) {
        float4 wq4 = *(const float4*)(wq  + i * HID + c0);
        float4 wk4 = *(const float4*)(wkE + i * HID + c0);
        float4 wv4 = *(const float4*)(wvE + i * HID + c0);
#pragma unroll
        for (int jr = 0; jr < 4; ++jr) {
          float ae = hE[r0 + jr][i];
          fma4(qq[jr], ae, wq4);
          fma4(kk[jr], ae, wk4);
          fma4(vv[jr], ae, wv4);
        }
      }
      float* kaf = (float*)&ka; float* vaf = (float*)&va;
#pragma unroll
      for (int jr = 0; jr < 4; ++jr) {
        *(float4*)&bufA[r0 + jr][c0] = make_float4(qq[jr][0], qq[jr][1], qq[jr][2], qq[jr][3]);
        float* kjf = (float*)&kj4[jr]; float* vjf = (float*)&vj4[jr];
#pragma unroll
        for (int j = 0; j < 4; ++j) {
          KtU[(c0 + j) * 33 + (r0 + jr)] = kk[jr][j] + kaf[j] + kjf[j];
          vv[jr][j] += vaf[j] + vjf[j];
        }
      }
    }
    __syncthreads();

    // C: logits (masked) -> att
    {
      const float scale = 0.17677669529663687f;  // 1/sqrt(32)
      for (int idx = tid; idx < NHEADS * KNB * KNB; idx += 256) {
        int h = idx / (KNB * KNB);
        int rem = idx % (KNB * KNB);
        int q = rem / KNB, k = rem % KNB;
        const float* qrow = &bufA[q][h * DHEAD];
        const float* krow = &KtU[(h * DHEAD) * 33 + k];
        float acc = 0.f;
#pragma unroll
        for (int d = 0; d < DHEAD; ++d) acc = fmaf(qrow[d], krow[d * 33], acc);
        acc *= scale;
        float m = ma[q] * ma[k];
        att[h][q][k] = (m > 0.f) ? acc : -3.4028234663852886e38f;
      }
    }
    __syncthreads();
    // softmax per (h,q) row; then all threads dump V(regs) -> bufA (Q is dead)
    if (tid < NHEADS * KNB) {
      int h = tid / KNB, q = tid % KNB;
      float mx = -3.4028234663852886e38f;
      for (int k = 0; k < KNB; ++k) mx = fmaxf(mx, att[h][q][k]);
      float s = 0.f;
      for (int k = 0; k < KNB; ++k) { float e = expf(att[h][q][k] - mx); att[h][q][k] = e; s += e; }
      float inv = 1.f / s;
      float mq = ma[q];
      for (int k = 0; k < KNB; ++k) att[h][q][k] = att[h][q][k] * inv * (mq * ma[k]);
    }
#pragma unroll
    for (int jr = 0; jr < 4; ++jr)
      *(float4*)&bufA[r0 + jr][c0] = make_float4(vv[jr][0], vv[jr][1], vv[jr][2], vv[jr][3]);
    __syncthreads();

    // E: upd = att @ V -> updf (aliases KtU, row-major [32][128])
    float* updf = KtU;
    {
      int h = cg >> 3;
      float u[4][4] = {{0.f}};
      for (int k = 0; k < KNB; ++k) {
        float4 v4 = *(const float4*)&bufA[k][c0];
#pragma unroll
        for (int jr = 0; jr < 4; ++jr) fma4(u[jr], att[h][r0 + jr][k], v4);
      }
#pragma unroll
      for (int jr = 0; jr < 4; ++jr)
#pragma unroll
        for (int j = 0; j < 4; ++j) updf[(r0 + jr) * HID + c0 + j] = u[jr][j];
    }
    __syncthreads();

    // F: dh = upd @ wo ; hE += dh
    {
      float acc[4][4] = {{0.f}};
      for (int i = 0; i < HID; ++i) {
        float4 w4 = *(const float4*)(wo + i * HID + c0);
#pragma unroll
        for (int jr = 0; jr < 4; ++jr) fma4(acc[jr], updf[(r0 + jr) * HID + i], w4);
      }
#pragma unroll
      for (int jr = 0; jr < 4; ++jr) {
        int r = r0 + jr;
        if (r < KNB) {
#pragma unroll
          for (int j = 0; j < 4; ++j) hE[r][c0 + j] += acc[jr][j];
        }
      }
    }
    __syncthreads();

    // G: LN1
    layer_norm(hE, l1g + l * HID, l1b + l * HID, 1.f, tid);
    __syncthreads();

    // H: FF in 4 chunks of 128 (chunk staged in bufA)
    {
      float facc[4][4] = {{0.f}};
      for (int ch = 0; ch < 4; ++ch) {
        float acc[4][4] = {{0.f}};
        for (int i = 0; i < HID; ++i) {
          float4 w4 = *(const float4*)(f1 + i * NFF + ch * HID + c0);
#pragma unroll
          for (int jr = 0; jr < 4; ++jr) fma4(acc[jr], hE[r0 + jr][i], w4);
        }
#pragma unroll
        for (int jr = 0; jr < 4; ++jr)
#pragma unroll
          for (int j = 0; j < 4; ++j)
            bufA[r0 + jr][c0 + j] = fmaxf(acc[jr][j] + b1[ch * HID + c0 + j], 0.f);
        __syncthreads();
        for (int i = 0; i < HID; ++i) {
          float4 w4 = *(const float4*)(f2 + (ch * HID + i) * HID + c0);
#pragma unroll
          for (int jr = 0; jr < 4; ++jr) fma4(facc[jr], bufA[r0 + jr][i], w4);
        }
        __syncthreads();
      }
#pragma unroll
      for (int jr = 0; jr < 4; ++jr) {
        int r = r0 + jr;
        if (r < KNB) {
#pragma unroll
          for (int j = 0; j < 4; ++j) hE[r][c0 + j] += facc[jr][j] + b2[c0 + j];
        }
      }
    }
    __syncthreads();

    // I: LN2 + x_mask multiply
    layer_norm(hE, l2g + l * HID, l2b + l * HID, mrow, tid);
    __syncthreads();
  }

  // ---------------- h_out = hE @ Wout + bout ----------------
  {
    float* gO = gOUT + (size_t)((b * NB + n) * KNB) * NOUT;
    for (int p = 0; p < 4; ++p) {
      int cc0 = p * HID + c0;
      if (cc0 < NOUT) {
        float acc[4][4] = {{0.f}};
        for (int i = 0; i < HID; ++i) {
          float4 w4 = *(const float4*)(Wout + i * NOUT + cc0);
#pragma unroll
          for (int jr = 0; jr < 4; ++jr) fma4(acc[jr], hE[r0 + jr][i], w4);
        }
        float4 b4 = *(const float4*)(bout + cc0);
#pragma unroll
        for (int jr = 0; jr < 4; ++jr) {
          int r = r0 + jr;
          if (r < KNB) {
            *(float4*)(gO + r * NOUT + cc0) =
                make_float4(acc[jr][0] + b4.x, acc[jr][1] + b4.y, acc[jr][2] + b4.z, acc[jr][3] + b4.w);
          }
        }
      }
    }
  }
}

// ---- merge_duplicate_edges ----
__global__ void k_clearT(int* __restrict__ T) {
  int i = blockIdx.x * 256 + threadIdx.x;
  if (i < 2 * NB * NB) T[i] = 0;
}
__global__ void k_buildT(const int* __restrict__ Eix, int* __restrict__ T) {
  int idx = blockIdx.x * 256 + threadIdx.x;   // 2*512*30
  if (idx < 2 * NB * KNB) {
    int b = idx / (NB * KNB);
    int rem = idx % (NB * KNB);
    int i = rem / KNB, k = rem % KNB;
    int j = Eix[idx];
    atomicMax(&T[(b * NB + i) * NB + j], k + 1);   // last-write-wins
  }
}
__global__ void k_merge(const float* __restrict__ HO, const int* __restrict__ Eix,
                        const int* __restrict__ T, float* __restrict__ out) {
  int gid = blockIdx.x * 256 + threadIdx.x;   // 2*512*30*100
  if (gid >= 2 * NB * KNB * (NOUT / 4)) return;
  int c4 = gid % (NOUT / 4);
  int bnk = gid / (NOUT / 4);
  int b = bnk / (NB * KNB);
  int n = (bnk / KNB) % NB;
  int j = Eix[bnk];
  int kp = T[(b * NB + j) * NB + n];
  float4 a = ((const float4*)HO)[(size_t)bnk * (NOUT / 4) + c4];
  float4 rv = make_float4(0.f, 0.f, 0.f, 0.f);
  if (kp > 0) rv = ((const float4*)HO)[(size_t)((b * NB + j) * KNB + (kp - 1)) * (NOUT / 4) + c4];
  ((float4*)out)[gid] = make_float4(0.5f * (a.x + rv.x), 0.5f * (a.y + rv.y),
                                    0.5f * (a.z + rv.z), 0.5f * (a.w + rv.w));
}

extern "C" void kernel_launch(void* const* d_in, const int* in_sizes, int n_in,
                              void* d_out, int out_size, void* d_ws, size_t ws_size,
                              hipStream_t stream) {
  const float* V   = (const float*)d_in[0];
  const float* E   = (const float*)d_in[1];
  const float* xmk = (const float*)d_in[2];
  const int*   Eix = (const int*)d_in[3];
  const float* Wv  = (const float*)d_in[4];
  const float* bv  = (const float*)d_in[5];
  const float* We  = (const float*)d_in[6];
  const float* be  = (const float*)d_in[7];
  const float* WQ  = (const float*)d_in[8];
  const float* WK  = (const float*)d_in[9];
  const float* WVp = (const float*)d_in[10];
  const float* WO  = (const float*)d_in[11];
  const float* l1g = (const float*)d_in[12];
  const float* l1b = (const float*)d_in[13];
  const float* l2g = (const float*)d_in[14];
  const float* l2b = (const float*)d_in[15];
  const float* f1w = (const float*)d_in[16];
  const float* f1b = (const float*)d_in[17];
  const float* f2w = (const float*)d_in[18];
  const float* f2b = (const float*)d_in[19];
  const float* Wou = (const float*)d_in[20];
  const float* bou = (const float*)d_in[21];

  // ws layout (floats): HO 12,288,000 | tbl 1,572,864 | hV 131,072  = 55.97 MB
  // T (524,288 ints) aliases tbl (tbl is dead after k_main, T built after).
  float* HO  = (float*)d_ws;
  float* tbl = HO + 12288000ull;
  float* hV  = tbl + 1572864ull;
  int*   T   = (int*)tbl;

  k_hv<<<512, 256, 0, stream>>>(V, Wv, bv, hV);
  k_tables<<<6144, 256, 0, stream>>>(hV, WK, WVp, tbl);
  k_main<<<1024, 256, 0, stream>>>(E, Eix, xmk, We, be, WQ, WK, WVp, WO,
                                   l1g, l1b, l2g, l2b, f1w, f1b, f2w, f2b,
                                   Wou, bou, tbl, HO);
  k_clearT<<<2048, 256, 0, stream>>>(T);
  k_buildT<<<120, 256, 0, stream>>>(Eix, T);
  k_merge<<<12000, 256, 0, stream>>>(HO, Eix, T, (float*)d_out);
}

// Round 3
// 342.665 us; speedup vs baseline: 6.6998x; 3.1939x over previous
//
#include <hip/hip_runtime.h>

#define NB 512
#define KNB 30
#define HID 128
#define NL 3
#define NOUT 400
#define NFF 512

typedef _Float16 f16;
typedef _Float16 f16x8 __attribute__((ext_vector_type(8)));
typedef _Float16 f16x4 __attribute__((ext_vector_type(4)));
typedef float f32x4 __attribute__((ext_vector_type(4)));

#define MFMA16(a, b, c) __builtin_amdgcn_mfma_f32_16x16x32_f16(a, b, c, 0, 0, 0)

// packed weight offsets (in f16 elements)
#define PK_WE   0
#define PK_WQ   16384
#define PK_WK   65536
#define PK_WV   114688
#define PK_WO   163840
#define PK_F1   212992
#define PK_F2   409600
#define PK_WOUT 606208
#define PK_TOTAL 657408

// ---------------- fp32 helper kernels (unchanged structure) ----------------
__global__ void k_hv(const float* __restrict__ V, const float* __restrict__ Wv,
                     const float* __restrict__ bv, float* __restrict__ hV) {
  int idx = blockIdx.x * 256 + threadIdx.x;
  int row = idx >> 7, c = idx & 127;
  const float* vr = V + row * HID;
  float acc = bv[c];
  for (int i = 0; i < HID; ++i) acc = fmaf(vr[i], Wv[i * HID + c], acc);
  hV[idx] = acc;
}

__global__ void k_tables(const float* __restrict__ hV, const float* __restrict__ WK,
                         const float* __restrict__ WVp, float* __restrict__ tbl) {
  int idx = blockIdx.x * 256 + threadIdx.x;   // 1,572,864
  int c = idx & 127;
  int row = (idx >> 7) & 1023;
  int t = idx >> 17;                 // 0..11
  int l = t >> 2, part = t & 3;
  const float* W;
  if (part == 0)      W = WK  + l * 3 * HID * HID;
  else if (part == 1) W = WK  + l * 3 * HID * HID + HID * HID;
  else if (part == 2) W = WVp + l * 3 * HID * HID;
  else                W = WVp + l * 3 * HID * HID + HID * HID;
  const float* hr = hV + row * HID;
  float acc = 0.f;
  for (int i = 0; i < HID; ++i) acc = fmaf(hr[i], W[i * HID + c], acc);
  tbl[idx] = acc;
}

// ---------------- weight packing: B-fragment order, f16 ----------------
__device__ __forceinline__ void pack_one(const float* W, int N, int r, f16* dst) {
  // packed layout: ((ks*NT + nt)*64 + lane)*8 + j ; element = W[(ks*32 + 8*(lane>>4)+j)*N + nt*16 + (lane&15)]
  int j = r & 7, l = (r >> 3) & 63, t = r >> 9;
  int NT = N >> 4;
  int nt = t % NT, ks = t / NT;
  int k = ks * 32 + ((l >> 4) << 3) + j;
  int c = nt * 16 + (l & 15);
  dst[r] = (f16)W[k * N + c];
}

__global__ void k_pack(const float* __restrict__ We, const float* __restrict__ WQ,
                       const float* __restrict__ WK, const float* __restrict__ WV,
                       const float* __restrict__ WO, const float* __restrict__ f1w,
                       const float* __restrict__ f2w, const float* __restrict__ Wout,
                       f16* __restrict__ P) {
  int idx = blockIdx.x * 256 + threadIdx.x;
  if (idx >= PK_TOTAL) return;
  const float* W; int N; int r; f16* dst;
  if (idx < 212992) {
    int s = idx >> 14; r = idx & 16383; N = 128;
    dst = P + (idx - r);
    if (s == 0) W = We;
    else if (s < 4) W = WQ + (s - 1) * 16384;
    else if (s < 7) W = WK + (s - 4) * 49152 + 32768;
    else if (s < 10) W = WV + (s - 7) * 49152 + 32768;
    else W = WO + (s - 10) * 16384;
  } else if (idx < 409600) {
    int t = (idx - 212992) >> 16; r = (idx - 212992) & 65535;
    W = f1w + t * 65536; N = 512; dst = P + 212992 + t * 65536;
  } else if (idx < 606208) {
    int t = (idx - 409600) >> 16; r = (idx - 409600) & 65535;
    W = f2w + t * 65536; N = 128; dst = P + 409600 + t * 65536;
  } else {
    r = idx - 606208; W = Wout; N = 400; dst = P + 606208;
  }
  pack_one(W, N, r, dst);
}

// ---------------- k_main building blocks ----------------
// type-A GEMM piece: 2 m-tiles x 2 n-tiles (nt0, nt1), K=128 (4 steps)
__device__ __forceinline__ void mfma_block8(const f16* Ab, int astr, const f16x8* B,
                                            int nt0, int nt1, f32x4 acc[2][2],
                                            int ln, int g, int lane) {
  f16x8 af[2][4];
#pragma unroll
  for (int mt = 0; mt < 2; ++mt)
#pragma unroll
    for (int ks = 0; ks < 4; ++ks)
      af[mt][ks] = *(const f16x8*)&Ab[(mt * 16 + ln) * astr + ks * 32 + g * 8];
#pragma unroll
  for (int ks = 0; ks < 4; ++ks) {
    f16x8 b0 = B[(ks * 8 + nt0) * 64 + lane];
    f16x8 b1 = B[(ks * 8 + nt1) * 64 + lane];
#pragma unroll
    for (int mt = 0; mt < 2; ++mt) {
      acc[mt][0] = MFMA16(af[mt][ks], b0, acc[mt][0]);
      acc[mt][1] = MFMA16(af[mt][ks], b1, acc[mt][1]);
    }
  }
}

__device__ __forceinline__ void layer_norm_cvt(float (*hEp)[132], f16* hEhp,
                                               const float* __restrict__ gg,
                                               const float* __restrict__ bb,
                                               float mmul, int tid) {
  int r = tid >> 3, g8 = tid & 7;
  if (r < KNB) {
    float x[16]; float s1 = 0.f, s2 = 0.f;
    int cb = g8 * 16;
#pragma unroll
    for (int m = 0; m < 16; ++m) { x[m] = hEp[r][cb + m]; s1 += x[m]; s2 += x[m] * x[m]; }
#pragma unroll
    for (int o = 1; o < 8; o <<= 1) { s1 += __shfl_xor(s1, o); s2 += __shfl_xor(s2, o); }
    float mu = s1 * (1.f / 128.f);
    float var = fmaf(-s1, mu, s2) * (1.f / 127.f);
    float inv = 1.f / (sqrtf(var + 1e-6f) + 1e-6f);
    f16x8 h0, h1;
#pragma unroll
    for (int m = 0; m < 16; ++m) {
      int c = cb + m;
      float y = (gg[c] * (x[m] - mu) * inv + bb[c]) * mmul;
      hEp[r][c] = y;
      if (m < 8) h0[m] = (f16)y; else h1[m - 8] = (f16)y;
    }
    *(f16x8*)&hEhp[r * 136 + cb] = h0;
    *(f16x8*)&hEhp[r * 136 + cb + 8] = h1;
  }
}

__launch_bounds__(256, 2)
__global__ void k_main(
    const float* __restrict__ E, const int* __restrict__ Eix, const float* __restrict__ xm,
    const float* __restrict__ be,
    const float* __restrict__ l1g, const float* __restrict__ l1b,
    const float* __restrict__ l2g, const float* __restrict__ l2b,
    const float* __restrict__ f1b, const float* __restrict__ f2b,
    const float* __restrict__ bout,
    const f16* __restrict__ P, const float* __restrict__ tbl,
    float* __restrict__ gOUT) {
  // LDS pool: hE fp32[32][132] | hEh f16[32][136] | poolB | ma | eidx
  __shared__ __align__(16) char SM[63744];
  float (*hE)[132] = (float(*)[132])SM;
  f16* hEh = (f16*)(SM + 16896);
  char* poolB = SM + 25600;
  f16* Qh   = (f16*)(poolB);            // [32][136]
  f16* Kh   = (f16*)(poolB + 8704);     // [32][136]
  f16* Vt   = (f16*)(poolB + 17408);    // [128][40]  (V transposed)
  f16* atth = (f16*)(poolB + 27648);    // [4][32][40]
  f16* hidh = (f16*)(poolB);            // [32][520], aliases Qh..atth (FF phase)
  float* ma = (float*)(SM + 63488);
  int* eidx = (int*)(SM + 63616);

  const int tid = threadIdx.x;
  const int bid = blockIdx.x;
  const int b = bid >> 9, n = bid & (NB - 1);
  const int lane = tid & 63, wv = tid >> 6;
  const int ln = lane & 15, g = lane >> 4;

  // zero hEh+poolB (46592 B) so never-written rows/cols are finite zeros
  {
    float4 z = make_float4(0.f, 0.f, 0.f, 0.f);
    float4* p = (float4*)(SM + 16896);
    for (int x = tid; x < 2912; x += 256) p[x] = z;
  }
  if (tid < 32) {
    int e = (tid < KNB) ? Eix[(b * NB + n) * KNB + tid] : 0;
    eidx[tid] = e;
    float mr = xm[b * NB + n];
    ma[tid] = (tid < KNB) ? mr * xm[b * NB + e] : 0.f;
  }
  __syncthreads();
  // E tile -> hEh f16 (rows < 30)
  {
    const float4* Eg = (const float4*)(E + (size_t)(b * NB + n) * KNB * HID);
    for (int x = tid; x < 960; x += 256) {
      float4 e4 = Eg[x];
      int r = x >> 5, c = (x & 31) << 2;
      f16x4 h; h[0] = (f16)e4.x; h[1] = (f16)e4.y; h[2] = (f16)e4.z; h[3] = (f16)e4.w;
      *(f16x4*)&hEh[r * 136 + c] = h;
    }
  }
  const float mrow = xm[b * NB + n];
  __syncthreads();

  // ---- init: hE = E @ We + be ----
  {
    f32x4 acc[2][2] = {};
    mfma_block8(hEh, 136, (const f16x8*)(P + PK_WE), wv, wv + 4, acc, ln, g, lane);
    __syncthreads();   // drain all a-frag reads before overwriting hEh
#pragma unroll
    for (int nts = 0; nts < 2; ++nts) {
      int c = (wv + nts * 4) * 16 + ln;
      float bev = be[c];
#pragma unroll
      for (int mt = 0; mt < 2; ++mt)
#pragma unroll
        for (int i = 0; i < 4; ++i) {
          int r = mt * 16 + 4 * g + i;
          if (r < KNB) {
            float v = acc[mt][nts][i] + bev;
            hE[r][c] = v;
            hEh[r * 136 + c] = (f16)v;
          }
        }
    }
  }
  __syncthreads();

  // ---------------- layers ----------------
  for (int l = 0; l < NL; ++l) {
    const f16x8* PQ = (const f16x8*)(P + PK_WQ + l * 16384);
    const f16x8* PKk = (const f16x8*)(P + PK_WK + l * 16384);
    const f16x8* PV = (const f16x8*)(P + PK_WV + l * 16384);
    const f16x8* PO = (const f16x8*)(P + PK_WO + l * 16384);
    const f16x8* P1 = (const f16x8*)(P + PK_F1 + l * 65536);
    const f16x8* P2 = (const f16x8*)(P + PK_F2 + l * 65536);
    const float* Ki = tbl + (size_t)(l * 4 + 0) * (2 * NB * HID) + (size_t)b * NB * HID;
    const float* Kj = tbl + (size_t)(l * 4 + 1) * (2 * NB * HID) + (size_t)b * NB * HID;
    const float* Vi = tbl + (size_t)(l * 4 + 2) * (2 * NB * HID) + (size_t)b * NB * HID;
    const float* Vj = tbl + (size_t)(l * 4 + 3) * (2 * NB * HID) + (size_t)b * NB * HID;

    // ---- QKV projections (fused, MFMA) ----
    {
      int e0v = eidx[0];
      int er[2][4];
#pragma unroll
      for (int mt = 0; mt < 2; ++mt)
#pragma unroll
        for (int i = 0; i < 4; ++i) er[mt][i] = eidx[mt * 16 + 4 * g + i];
      float kib[2], vib[2], kjv[2][2][4], vjv[2][2][4];
#pragma unroll
      for (int nts = 0; nts < 2; ++nts) {
        int c = (wv + nts * 4) * 16 + ln;
        kib[nts] = Ki[e0v * 128 + c];
        vib[nts] = Vi[e0v * 128 + c];
#pragma unroll
        for (int mt = 0; mt < 2; ++mt)
#pragma unroll
          for (int i = 0; i < 4; ++i) {
            kjv[nts][mt][i] = Kj[er[mt][i] * 128 + c];
            vjv[nts][mt][i] = Vj[er[mt][i] * 128 + c];
          }
      }
      f32x4 qa[2][2] = {}, kk[2][2] = {}, va[2][2] = {};
      mfma_block8(hEh, 136, PQ, wv, wv + 4, qa, ln, g, lane);
      mfma_block8(hEh, 136, PKk, wv, wv + 4, kk, ln, g, lane);
      mfma_block8(hEh, 136, PV, wv, wv + 4, va, ln, g, lane);
#pragma unroll
      for (int nts = 0; nts < 2; ++nts) {
        int c = (wv + nts * 4) * 16 + ln;
#pragma unroll
        for (int mt = 0; mt < 2; ++mt)
#pragma unroll
          for (int i = 0; i < 4; ++i) {
            int r = mt * 16 + 4 * g + i;
            Qh[r * 136 + c] = (f16)qa[mt][nts][i];
            Kh[r * 136 + c] = (f16)(kk[mt][nts][i] + kib[nts] + kjv[nts][mt][i]);
            Vt[c * 40 + r]  = (f16)(va[mt][nts][i] + vib[nts] + vjv[nts][mt][i]);
          }
      }
    }
    __syncthreads();

    // ---- attention: logits (MFMA) -> in-register softmax -> upd (MFMA). wave = head ----
    {
      int h = wv;
      f16* ath = atth + h * 1280;
      f16x8 qf[2], kf[2];
#pragma unroll
      for (int mt = 0; mt < 2; ++mt)
        qf[mt] = *(const f16x8*)&Qh[(mt * 16 + ln) * 136 + h * 32 + g * 8];
#pragma unroll
      for (int nt = 0; nt < 2; ++nt)
        kf[nt] = *(const f16x8*)&Kh[(nt * 16 + ln) * 136 + h * 32 + g * 8];
      f32x4 s[2][2] = {};
#pragma unroll
      for (int mt = 0; mt < 2; ++mt)
#pragma unroll
        for (int nt = 0; nt < 2; ++nt) s[mt][nt] = MFMA16(qf[mt], kf[nt], s[mt][nt]);
      float mk0 = ma[ln], mk1 = ma[16 + ln];
      const float scale = 0.17677669529663687f;
#pragma unroll
      for (int mt = 0; mt < 2; ++mt) {
#pragma unroll
        for (int i = 0; i < 4; ++i) {
          int q = mt * 16 + 4 * g + i;
          float mq = ma[q];
          float v0 = s[mt][0][i] * scale;
          float v1 = s[mt][1][i] * scale;
          v0 = (mq * mk0 > 0.f) ? v0 : -3.4028234663852886e38f;
          v1 = (mq * mk1 > 0.f) ? v1 : -3.4028234663852886e38f;
          float mx = fmaxf(v0, v1);
          mx = fmaxf(mx, __shfl_xor(mx, 1));
          mx = fmaxf(mx, __shfl_xor(mx, 2));
          mx = fmaxf(mx, __shfl_xor(mx, 4));
          mx = fmaxf(mx, __shfl_xor(mx, 8));
          float e0 = __expf(v0 - mx), e1 = __expf(v1 - mx);
          float sm = e0 + e1;
          sm += __shfl_xor(sm, 1); sm += __shfl_xor(sm, 2);
          sm += __shfl_xor(sm, 4); sm += __shfl_xor(sm, 8);
          float inv = 1.f / sm;
          ath[q * 40 + ln]      = (f16)(e0 * inv * (mq * mk0));
          ath[q * 40 + 16 + ln] = (f16)(e1 * inv * (mq * mk1));
        }
      }
      asm volatile("s_waitcnt lgkmcnt(0)" ::: "memory");
      __builtin_amdgcn_sched_barrier(0);
      // upd = att @ V  (head cols) -> updh (= hEh alias)
      f32x4 u[2][2] = {};
      f16x8 aat[2], vbf[2];
#pragma unroll
      for (int mt = 0; mt < 2; ++mt)
        aat[mt] = *(const f16x8*)&ath[(mt * 16 + ln) * 40 + g * 8];
#pragma unroll
      for (int nt = 0; nt < 2; ++nt)
        vbf[nt] = *(const f16x8*)&Vt[((2 * h + nt) * 16 + ln) * 40 + g * 8];
#pragma unroll
      for (int mt = 0; mt < 2; ++mt)
#pragma unroll
        for (int nt = 0; nt < 2; ++nt) u[mt][nt] = MFMA16(aat[mt], vbf[nt], u[mt][nt]);
#pragma unroll
      for (int mt = 0; mt < 2; ++mt)
#pragma unroll
        for (int nt = 0; nt < 2; ++nt)
#pragma unroll
          for (int i = 0; i < 4; ++i) {
            int r = mt * 16 + 4 * g + i;
            hEh[r * 136 + h * 32 + nt * 16 + ln] = (f16)u[mt][nt][i];
          }
    }
    __syncthreads();

    // ---- dh = upd @ wo ; hE += dh ----
    {
      f32x4 acc[2][2] = {};
      mfma_block8(hEh, 136, PO, wv, wv + 4, acc, ln, g, lane);
#pragma unroll
      for (int nts = 0; nts < 2; ++nts) {
        int c = (wv + nts * 4) * 16 + ln;
#pragma unroll
        for (int mt = 0; mt < 2; ++mt)
#pragma unroll
          for (int i = 0; i < 4; ++i) {
            int r = mt * 16 + 4 * g + i;
            if (r < KNB) hE[r][c] += acc[mt][nts][i];
          }
      }
    }
    __syncthreads();
    layer_norm_cvt(hE, hEh, l1g + l * HID, l1b + l * HID, 1.f, tid);
    __syncthreads();

    // ---- FF1: hid = relu(hEh @ f1 + b1) -> hidh (full 512) ----
    {
      f16x8 af[2][4];
#pragma unroll
      for (int mt = 0; mt < 2; ++mt)
#pragma unroll
        for (int ks = 0; ks < 4; ++ks)
          af[mt][ks] = *(const f16x8*)&hEh[(mt * 16 + ln) * 136 + ks * 32 + g * 8];
      f32x4 acc[2][8] = {};
#pragma unroll
      for (int ks = 0; ks < 4; ++ks)
#pragma unroll
        for (int t = 0; t < 8; ++t) {
          f16x8 bv = P1[(ks * 32 + wv + 4 * t) * 64 + lane];
          acc[0][t] = MFMA16(af[0][ks], bv, acc[0][t]);
          acc[1][t] = MFMA16(af[1][ks], bv, acc[1][t]);
        }
      const float* b1 = f1b + l * NFF;
#pragma unroll
      for (int t = 0; t < 8; ++t) {
        int c = (wv + 4 * t) * 16 + ln;
        float b1v = b1[c];
#pragma unroll
        for (int mt = 0; mt < 2; ++mt)
#pragma unroll
          for (int i = 0; i < 4; ++i) {
            int r = mt * 16 + 4 * g + i;
            hidh[r * 520 + c] = (f16)fmaxf(acc[mt][t][i] + b1v, 0.f);
          }
      }
    }
    __syncthreads();

    // ---- FF2: hE += hidh @ f2 + b2 ----
    {
      f32x4 acc[2][2] = {};
#pragma unroll
      for (int ks = 0; ks < 16; ++ks) {
        f16x8 a0 = *(const f16x8*)&hidh[ln * 520 + ks * 32 + g * 8];
        f16x8 a1 = *(const f16x8*)&hidh[(16 + ln) * 520 + ks * 32 + g * 8];
        f16x8 b0 = P2[(ks * 8 + wv) * 64 + lane];
        f16x8 b1 = P2[(ks * 8 + wv + 4) * 64 + lane];
        acc[0][0] = MFMA16(a0, b0, acc[0][0]);
        acc[0][1] = MFMA16(a0, b1, acc[0][1]);
        acc[1][0] = MFMA16(a1, b0, acc[1][0]);
        acc[1][1] = MFMA16(a1, b1, acc[1][1]);
      }
      const float* b2 = f2b + l * HID;
#pragma unroll
      for (int nts = 0; nts < 2; ++nts) {
        int c = (wv + nts * 4) * 16 + ln;
        float b2v = b2[c];
#pragma unroll
        for (int mt = 0; mt < 2; ++mt)
#pragma unroll
          for (int i = 0; i < 4; ++i) {
            int r = mt * 16 + 4 * g + i;
            if (r < KNB) hE[r][c] += acc[mt][nts][i] + b2v;
          }
      }
    }
    __syncthreads();
    layer_norm_cvt(hE, hEh, l2g + l * HID, l2b + l * HID, mrow, tid);
    __syncthreads();
  }

  // ---- h_out = hEh @ Wout + bout -> global ----
  {
    float* gO = gOUT + (size_t)((b * NB + n) * KNB) * NOUT;
    f16x8 af[2][4];
#pragma unroll
    for (int mt = 0; mt < 2; ++mt)
#pragma unroll
      for (int ks = 0; ks < 4; ++ks)
        af[mt][ks] = *(const f16x8*)&hEh[(mt * 16 + ln) * 136 + ks * 32 + g * 8];
    const f16x8* PW = (const f16x8*)(P + PK_WOUT);
#pragma unroll
    for (int mt = 0; mt < 2; ++mt) {
      for (int nt = wv; nt < 25; nt += 4) {
        f32x4 acc = {};
#pragma unroll
        for (int ks = 0; ks < 4; ++ks) {
          f16x8 bv = PW[(ks * 25 + nt) * 64 + lane];
          acc = MFMA16(af[mt][ks], bv, acc);
        }
        int c = nt * 16 + ln;
        float bo = bout[c];
#pragma unroll
        for (int i = 0; i < 4; ++i) {
          int r = mt * 16 + 4 * g + i;
          if (r < KNB) gO[r * 400 + c] = acc[i] + bo;
        }
      }
    }
  }
}

// ---- merge_duplicate_edges ----
__global__ void k_clearT(int* __restrict__ T) {
  int i = blockIdx.x * 256 + threadIdx.x;
  if (i < 2 * NB * NB) T[i] = 0;
}
__global__ void k_buildT(const int* __restrict__ Eix, int* __restrict__ T) {
  int idx = blockIdx.x * 256 + threadIdx.x;
  if (idx < 2 * NB * KNB) {
    int b = idx / (NB * KNB);
    int rem = idx % (NB * KNB);
    int i = rem / KNB, k = rem % KNB;
    int j = Eix[idx];
    atomicMax(&T[(b * NB + i) * NB + j], k + 1);
  }
}
__global__ void k_merge(const float* __restrict__ HO, const int* __restrict__ Eix,
                        const int* __restrict__ T, float* __restrict__ out) {
  int gid = blockIdx.x * 256 + threadIdx.x;
  if (gid >= 2 * NB * KNB * (NOUT / 4)) return;
  int c4 = gid % (NOUT / 4);
  int bnk = gid / (NOUT / 4);
  int b = bnk / (NB * KNB);
  int n = (bnk / KNB) % NB;
  int j = Eix[bnk];
  int kp = T[(b * NB + j) * NB + n];
  float4 a = ((const float4*)HO)[(size_t)bnk * (NOUT / 4) + c4];
  float4 rv = make_float4(0.f, 0.f, 0.f, 0.f);
  if (kp > 0) rv = ((const float4*)HO)[(size_t)((b * NB + j) * KNB + (kp - 1)) * (NOUT / 4) + c4];
  ((float4*)out)[gid] = make_float4(0.5f * (a.x + rv.x), 0.5f * (a.y + rv.y),
                                    0.5f * (a.z + rv.z), 0.5f * (a.w + rv.w));
}

extern "C" void kernel_launch(void* const* d_in, const int* in_sizes, int n_in,
                              void* d_out, int out_size, void* d_ws, size_t ws_size,
                              hipStream_t stream) {
  const float* V   = (const float*)d_in[0];
  const float* E   = (const float*)d_in[1];
  const float* xmk = (const float*)d_in[2];
  const int*   Eix = (const int*)d_in[3];
  const float* Wv  = (const float*)d_in[4];
  const float* bv  = (const float*)d_in[5];
  const float* We  = (const float*)d_in[6];
  const float* be  = (const float*)d_in[7];
  const float* WQ  = (const float*)d_in[8];
  const float* WK  = (const float*)d_in[9];
  const float* WVp = (const float*)d_in[10];
  const float* WO  = (const float*)d_in[11];
  const float* l1g = (const float*)d_in[12];
  const float* l1b = (const float*)d_in[13];
  const float* l2g = (const float*)d_in[14];
  const float* l2b = (const float*)d_in[15];
  const float* f1w = (const float*)d_in[16];
  const float* f1b = (const float*)d_in[17];
  const float* f2w = (const float*)d_in[18];
  const float* f2b = (const float*)d_in[19];
  const float* Wou = (const float*)d_in[20];
  const float* bou = (const float*)d_in[21];

  // ws (floats): HO 12,288,000 | tbl 1,572,864 | hV 131,072 | P (f16) 657,408
  // T (2MB) aliases tbl (tbl dead after k_main).
  float* HO  = (float*)d_ws;
  float* tbl = HO + 12288000ull;
  float* hV  = tbl + 1572864ull;
  f16*   P   = (f16*)(hV + 131072ull);
  int*   T   = (int*)tbl;

  k_hv<<<512, 256, 0, stream>>>(V, Wv, bv, hV);
  k_tables<<<6144, 256, 0, stream>>>(hV, WK, WVp, tbl);
  k_pack<<<2568, 256, 0, stream>>>(We, WQ, WK, WVp, WO, f1w, f2w, Wou, P);
  k_main<<<1024, 256, 0, stream>>>(E, Eix, xmk, be, l1g, l1b, l2g, l2b,
                                   f1b, f2b, bou, P, tbl, HO);
  k_clearT<<<2048, 256, 0, stream>>>(T);
  k_buildT<<<120, 256, 0, stream>>>(Eix, T);
  k_merge<<<12000, 256, 0, stream>>>(HO, Eix, T, (float*)d_out);
}